// Round 15
// baseline (3174.283 us; speedup 1.0000x reference)
//
#include <hip/hip_runtime.h>
#include <hip/hip_bf16.h>
#include <stdint.h>

typedef __hip_bfloat16 bf16;
typedef __attribute__((ext_vector_type(8))) short short8;
typedef __attribute__((ext_vector_type(4))) float f32x4;
typedef __attribute__((ext_vector_type(4))) unsigned int u32x4;
typedef __attribute__((ext_vector_type(2))) unsigned int u32x2;

#define NN 65536
#define DD 512
#define EE 1048576
#define GG 128
#define LL 512

static __device__ __forceinline__ void gld_lds16(const void* g, void* l) {
  __builtin_amdgcn_global_load_lds((const __attribute__((address_space(1))) uint32_t*)g,
                                   (__attribute__((address_space(3))) uint32_t*)l, 16, 0, 0);
}

// ---------------- prep: transpose/cast weights to bf16 ----------------
__global__ __launch_bounds__(256) void k_prep(
    const float* __restrict__ Wc, const float* __restrict__ Wf1, const float* __restrict__ Wf2,
    const float* __restrict__ Wih, const float* __restrict__ Whh,
    bf16* __restrict__ WcT, bf16* __restrict__ Wf1T, bf16* __restrict__ Wf2T,
    bf16* __restrict__ WihB, bf16* __restrict__ WhhB)
{
  const int i = blockIdx.x * 256 + threadIdx.x;
  if (i < 512 * 512) {
    const int k = i >> 9, n = i & 511;
    WcT [n * 512 + k] = __float2bfloat16(Wc [i]);
    Wf1T[n * 512 + k] = __float2bfloat16(Wf1[i]);
    Wf2T[n * 512 + k] = __float2bfloat16(Wf2[i]);
  }
  if (i < 1536 * 512) {
    WihB[i] = __float2bfloat16(Wih[i]);
    WhhB[i] = __float2bfloat16(Whh[i]);
  }
}

// ---------------- cast node features to bf16 ----------------
__global__ __launch_bounds__(256) void k_cast(const float* __restrict__ f, bf16* __restrict__ o) {
  const long i = (long)(blockIdx.x * 256 + threadIdx.x) * 4;
  const float4 v = *(const float4*)&f[i];
  union { bf16 b[4]; ushort4 u; } pk;
  pk.b[0] = __float2bfloat16(v.x);
  pk.b[1] = __float2bfloat16(v.y);
  pk.b[2] = __float2bfloat16(v.z);
  pk.b[3] = __float2bfloat16(v.w);
  *(ushort4*)&o[i] = pk.u;
}

// ---------------- CSR build ----------------
__global__ __launch_bounds__(256) void k_deg(const int* __restrict__ dst, int* __restrict__ deg) {
  const int e = blockIdx.x * 256 + threadIdx.x;
  atomicAdd(&deg[dst[e]], 1);
}

__global__ __launch_bounds__(1024) void k_scan1(const int* __restrict__ deg,
                                                int* __restrict__ roff, int* __restrict__ partial) {
  __shared__ int sd[1024];
  const int t = threadIdx.x, b = blockIdx.x, i = b * 1024 + t;
  const int v = deg[i];
  sd[t] = v;
  __syncthreads();
  for (int off = 1; off < 1024; off <<= 1) {
    int add = (t >= off) ? sd[t - off] : 0;
    __syncthreads();
    sd[t] += add;
    __syncthreads();
  }
  roff[i] = sd[t] - v;
  if (t == 1023) partial[b] = sd[t];
}

__global__ __launch_bounds__(64) void k_scan2(const int* __restrict__ partial, int* __restrict__ base) {
  __shared__ int sd[64];
  const int t = threadIdx.x;
  const int v = partial[t];
  sd[t] = v;
  __syncthreads();
  for (int off = 1; off < 64; off <<= 1) {
    int add = (t >= off) ? sd[t - off] : 0;
    __syncthreads();
    sd[t] += add;
    __syncthreads();
  }
  base[t] = sd[t] - v;
  if (t == 63) base[64] = sd[63];
}

__global__ __launch_bounds__(1024) void k_scan3(const int* __restrict__ base,
                                                int* __restrict__ roff, int* __restrict__ cursor) {
  const int b = blockIdx.x, t = threadIdx.x, i = b * 1024 + t;
  const int v = roff[i] + base[b];
  roff[i] = v;
  cursor[i] = v;
  if (i == 0) roff[NN] = base[64];
}

__global__ __launch_bounds__(256) void k_fill(const int* __restrict__ src, const int* __restrict__ dst,
                                              int* __restrict__ cursor, int* __restrict__ csr) {
  const int e = blockIdx.x * 256 + threadIdx.x;
  const int p = atomicAdd(&cursor[dst[e]], 1);
  csr[p] = src[e];
}

// ---------------- mean aggregation (bf16 gather, fp32 accum, 4-wide ILP) ----------------
__global__ __launch_bounds__(128) void k_agg(
    const bf16* __restrict__ featsb, const int* __restrict__ csr,
    const int* __restrict__ roff, bf16* __restrict__ agg)
{
  const int n = blockIdx.x, t = threadIdx.x;
  const int s0 = roff[n], s1 = roff[n + 1];
  float a0 = 0.f, a1 = 0.f, a2 = 0.f, a3 = 0.f;
  int i = s0;
  for (; i + 4 <= s1; i += 4) {
    const int sA = csr[i], sB = csr[i + 1], sC = csr[i + 2], sD = csr[i + 3];
    const ushort4 vA = *(const ushort4*)&featsb[(long)sA * 512 + t * 4];
    const ushort4 vB = *(const ushort4*)&featsb[(long)sB * 512 + t * 4];
    const ushort4 vC = *(const ushort4*)&featsb[(long)sC * 512 + t * 4];
    const ushort4 vD = *(const ushort4*)&featsb[(long)sD * 512 + t * 4];
    union { uint32_t u; float f; } c;
    c.u = (uint32_t)vA.x << 16; a0 += c.f;  c.u = (uint32_t)vA.y << 16; a1 += c.f;
    c.u = (uint32_t)vA.z << 16; a2 += c.f;  c.u = (uint32_t)vA.w << 16; a3 += c.f;
    c.u = (uint32_t)vB.x << 16; a0 += c.f;  c.u = (uint32_t)vB.y << 16; a1 += c.f;
    c.u = (uint32_t)vB.z << 16; a2 += c.f;  c.u = (uint32_t)vB.w << 16; a3 += c.f;
    c.u = (uint32_t)vC.x << 16; a0 += c.f;  c.u = (uint32_t)vC.y << 16; a1 += c.f;
    c.u = (uint32_t)vC.z << 16; a2 += c.f;  c.u = (uint32_t)vC.w << 16; a3 += c.f;
    c.u = (uint32_t)vD.x << 16; a0 += c.f;  c.u = (uint32_t)vD.y << 16; a1 += c.f;
    c.u = (uint32_t)vD.z << 16; a2 += c.f;  c.u = (uint32_t)vD.w << 16; a3 += c.f;
  }
  for (; i < s1; ++i) {
    const int s = csr[i];
    const ushort4 v = *(const ushort4*)&featsb[(long)s * 512 + t * 4];
    union { uint32_t u; float f; } c;
    c.u = (uint32_t)v.x << 16; a0 += c.f;  c.u = (uint32_t)v.y << 16; a1 += c.f;
    c.u = (uint32_t)v.z << 16; a2 += c.f;  c.u = (uint32_t)v.w << 16; a3 += c.f;
  }
  const float sc = 1.f / fmaxf((float)(s1 - s0), 1.f);
  union { bf16 b[4]; ushort4 u; } pk;
  pk.b[0] = __float2bfloat16(a0 * sc);
  pk.b[1] = __float2bfloat16(a1 * sc);
  pk.b[2] = __float2bfloat16(a2 * sc);
  pk.b[3] = __float2bfloat16(a3 * sc);
  *(ushort4*)&agg[(long)n * 512 + t * 4] = pk.u;
}

// ---------------- bf16 GEMM: C[M,Ncols] = A[M,512] @ Bt[Ncols,512]^T + bias ----------------
template<bool GATHER, bool RELU>
__global__ __launch_bounds__(256) void k_gemm(
    const bf16* __restrict__ A, const bf16* __restrict__ Bt,
    const float* __restrict__ bias, const int* __restrict__ gidx,
    bf16* __restrict__ outb, int Ncols)
{
  __shared__ bf16 lsA[128 * 64];
  __shared__ bf16 lsB[128 * 64];
  const int t = threadIdx.x;
  const int lane = t & 63, wid = t >> 6;
  const int wr = wid >> 1, wc = wid & 1;
  const int tm = blockIdx.y * 128, tn = blockIdx.x * 128;
  const int col8 = (t & 7) * 8;
  const int rsub = t >> 3;
  const int lc = lane & 15, lk = lane >> 4;

  long arow[4], brow[4];
#pragma unroll
  for (int i = 0; i < 4; ++i) {
    const int r = tm + i * 32 + rsub;
    int ar = r;
    if constexpr (GATHER) ar = gidx[r];
    arow[i] = (long)ar * 512;
    brow[i] = (long)(tn + i * 32 + rsub) * 512;
  }

  f32x4 acc[4][4];
#pragma unroll
  for (int a = 0; a < 4; ++a)
#pragma unroll
    for (int b = 0; b < 4; ++b) acc[a][b] = (f32x4){0.f, 0.f, 0.f, 0.f};

  for (int ks = 0; ks < 8; ++ks) {
    const int k0 = ks * 64;
#pragma unroll
    for (int i = 0; i < 4; ++i) {
      gld_lds16(A  + arow[i] + k0 + col8, &lsA[i * 2048 + t * 8]);
      gld_lds16(Bt + brow[i] + k0 + col8, &lsB[i * 2048 + t * 8]);
    }
    __syncthreads();
#pragma unroll
    for (int kk = 0; kk < 2; ++kk) {
      short8 af[4], bfr[4];
#pragma unroll
      for (int mi = 0; mi < 4; ++mi)
        af[mi] = *(const short8*)&lsA[(wr * 64 + mi * 16 + lc) * 64 + kk * 32 + lk * 8];
#pragma unroll
      for (int ni = 0; ni < 4; ++ni)
        bfr[ni] = *(const short8*)&lsB[(wc * 64 + ni * 16 + lc) * 64 + kk * 32 + lk * 8];
#pragma unroll
      for (int mi = 0; mi < 4; ++mi)
#pragma unroll
        for (int ni = 0; ni < 4; ++ni)
          acc[mi][ni] = __builtin_amdgcn_mfma_f32_16x16x32_bf16(af[mi], bfr[ni], acc[mi][ni], 0, 0, 0);
    }
    __syncthreads();
  }

  float bv[4];
#pragma unroll
  for (int ni = 0; ni < 4; ++ni) bv[ni] = bias[tn + wc * 64 + ni * 16 + lc];

#pragma unroll
  for (int mi = 0; mi < 4; ++mi) {
    const int r0 = tm + wr * 64 + mi * 16 + lk * 4;
#pragma unroll
    for (int j = 0; j < 4; ++j) {
      const int row = r0 + j;
      const long orow = (long)row * Ncols;
#pragma unroll
      for (int ni = 0; ni < 4; ++ni) {
        float v = acc[mi][ni][j] + bv[ni];
        if constexpr (RELU) v = fmaxf(v, 0.f);
        const int c = tn + wc * 64 + ni * 16 + lc;
        outb[orow + c] = __float2bfloat16(v);
      }
    }
  }
}

// ---------------- ff2 GEMM reading ys2 layout, scatter output ----------------
// ys2 element (g,l,k):  byte = ((l*8 + (g>>4))*32 + (k>>4))*512 + (g&15)*32 + (k&15)*2
__global__ __launch_bounds__(256) void k_gemm_ys(
    const uint8_t* __restrict__ Ay, const bf16* __restrict__ Bt,
    const float* __restrict__ bias, const int* __restrict__ gidx,
    float* __restrict__ outf)
{
  __shared__ bf16 lsA[128 * 64];
  __shared__ bf16 lsB[128 * 64];
  const int t = threadIdx.x;
  const int lane = t & 63, wid = t >> 6;
  const int wr = wid >> 1, wc = wid & 1;
  const int tm = blockIdx.y * 128, tn = blockIdx.x * 128;
  const int col8 = (t & 7) * 8;
  const int rsub = t >> 3;
  const int lc = lane & 15, lk = lane >> 4;

  long arow[4], brow[4];
#pragma unroll
  for (int i = 0; i < 4; ++i) {
    const int r = tm + i * 32 + rsub;
    const int g = r >> 9, l = r & 511;
    arow[i] = ((long)l * 8 + (g >> 4)) * 16384 + (g & 15) * 32;
    brow[i] = (long)(tn + i * 32 + rsub) * 512;
  }

  f32x4 acc[4][4];
#pragma unroll
  for (int a = 0; a < 4; ++a)
#pragma unroll
    for (int b = 0; b < 4; ++b) acc[a][b] = (f32x4){0.f, 0.f, 0.f, 0.f};

  for (int ks = 0; ks < 8; ++ks) {
    const int k0 = ks * 64;
    const int kk16 = k0 + col8;
    const long aoff = ((long)(kk16 >> 4) << 9) + ((kk16 & 15) << 1);
#pragma unroll
    for (int i = 0; i < 4; ++i) {
      gld_lds16(Ay + arow[i] + aoff, &lsA[i * 2048 + t * 8]);
      gld_lds16(Bt + brow[i] + k0 + col8, &lsB[i * 2048 + t * 8]);
    }
    __syncthreads();
#pragma unroll
    for (int kk = 0; kk < 2; ++kk) {
      short8 af[4], bfr[4];
#pragma unroll
      for (int mi = 0; mi < 4; ++mi)
        af[mi] = *(const short8*)&lsA[(wr * 64 + mi * 16 + lc) * 64 + kk * 32 + lk * 8];
#pragma unroll
      for (int ni = 0; ni < 4; ++ni)
        bfr[ni] = *(const short8*)&lsB[(wc * 64 + ni * 16 + lc) * 64 + kk * 32 + lk * 8];
#pragma unroll
      for (int mi = 0; mi < 4; ++mi)
#pragma unroll
        for (int ni = 0; ni < 4; ++ni)
          acc[mi][ni] = __builtin_amdgcn_mfma_f32_16x16x32_bf16(af[mi], bfr[ni], acc[mi][ni], 0, 0, 0);
    }
    __syncthreads();
  }

  float bv[4];
#pragma unroll
  for (int ni = 0; ni < 4; ++ni) bv[ni] = bias[tn + wc * 64 + ni * 16 + lc];

#pragma unroll
  for (int mi = 0; mi < 4; ++mi) {
    const int r0 = tm + wr * 64 + mi * 16 + lk * 4;
#pragma unroll
    for (int j = 0; j < 4; ++j) {
      const int row = r0 + j;
      const long orow = (long)gidx[row] * 512;
#pragma unroll
      for (int ni = 0; ni < 4; ++ni) {
        const int c = tn + wc * 64 + ni * 16 + lc;
        outf[orow + c] = acc[mi][ni][j] + bv[ni];
      }
    }
  }
}

// ---------------- persistent GRU v15: dual-chain interleave, r12 protocol ----------
// Per-chain protocol byte-identical to r12 (gi-before-poll; padded 128B
// per-producer flags; sc0 sc1 h store -> vmcnt(0) -> agent stamp; same ys2
// layout -> k_gemm_ys unchanged). NEW: each wave serves producer p for TWO
// independent chains (c, c+4), interleaving full phases. While chain A's
// stamps propagate (the 1-2k cyc r12 spent spinning), the wave executes
// chain B's entire phase — on return, A's flags are already visible, so the
// poll cost collapses. Whh's LDS slice depends only on d-columns, so both
// chains share lsW and biases. 64 blocks x 128 thr = 8 chains x 32 producers.
// No new sync constructs; worst case (no overlap) degenerates to r12 speed.
#define GRU_PHASE(CCH, CF, MF, GR, GZ, GN, HREG, PST)                                       \
  {                                                                                          \
    f32x4 acc[3] = { (f32x4){0.f,0.f,0.f,0.f}, (f32x4){0.f,0.f,0.f,0.f},                     \
                     (f32x4){0.f,0.f,0.f,0.f} };                                             \
    if (l > 0) {                                                                             \
      int ok;                                                                                \
      do {                                                                                   \
        const int v = __hip_atomic_load(&(CF)[(lane & 31) * 32], __ATOMIC_RELAXED,           \
                                        __HIP_MEMORY_SCOPE_AGENT);                           \
        ok = __all(v >= l);                                                                  \
      } while (!ok);                                                                         \
      asm volatile("" ::: "memory");                                                         \
      const uint8_t* pb = ys2 + ((long)(l - 1) * 8 + (CCH)) * 16384 + laneoff;               \
      u32x4 hv[16];                                                                          \
      _Pragma("unroll")                                                                      \
      for (int q = 0; q < 4; ++q) {                                                          \
        const uint8_t* pbq = pb + q * 4096;                                                  \
        _Pragma("unroll")                                                                    \
        for (int r2 = 0; r2 < 4; ++r2)                                                       \
          asm volatile("global_load_dwordx4 %0, %1, off offset:%2 sc0 sc1"                   \
                       : "=v"(hv[q * 4 + r2]) : "v"(pbq), "n"(r2 * 1024) : "memory");        \
      }                                                                                      \
      asm volatile("s_waitcnt vmcnt(0)" ::: "memory");                                       \
      __builtin_amdgcn_sched_barrier(0);                                                     \
      _Pragma("unroll")                                                                      \
      for (int kk = 0; kk < 16; ++kk) {                                                      \
        union { u32x4 u; short8 s; } cv;                                                     \
        cv.u = hv[kk];                                                                       \
        _Pragma("unroll")                                                                    \
        for (int gate = 0; gate < 3; ++gate) {                                               \
          const short8 wfr = *(const short8*)&lsW[(gate * 32 + w * 16 + lc) * 520            \
                                                  + kk * 32 + lk * 8];                       \
          acc[gate] = __builtin_amdgcn_mfma_f32_16x16x32_bf16(wfr, cv.s, acc[gate], 0, 0, 0);\
        }                                                                                    \
      }                                                                                      \
    } else {                                                                                 \
      asm volatile("s_waitcnt vmcnt(0)" ::: "memory");                                       \
      __builtin_amdgcn_sched_barrier(0);                                                     \
    }                                                                                        \
    uint32_t hb[4];                                                                          \
    _Pragma("unroll")                                                                        \
    for (int j = 0; j < 4; ++j) {                                                            \
      const uint32_t sh = (j & 1) * 16;                                                      \
      union { uint32_t u; float f; } cR, cZ, cN;                                             \
      cR.u = (((GR)[j >> 1] >> sh) & 0xffffu) << 16;                                         \
      cZ.u = (((GZ)[j >> 1] >> sh) & 0xffffu) << 16;                                         \
      cN.u = (((GN)[j >> 1] >> sh) & 0xffffu) << 16;                                         \
      const float r = 1.f / (1.f + __expf(-(cR.f + acc[0][j] + bRa[j])));                    \
      const float z = 1.f / (1.f + __expf(-(cZ.f + acc[1][j] + bZa[j])));                    \
      const float x2 = cN.f + r * (acc[2][j] + bNa[j]);                                      \
      const float ex = __expf(2.f * x2);                                                     \
      const float n = 1.f - 2.f / (ex + 1.f);                                                \
      const float hn = (1.f - z) * n + z * (HREG)[j];                                        \
      (HREG)[j] = hn;                                                                        \
      const bf16 hnb = __float2bfloat16(hn);                                                 \
      hb[j] = (uint32_t)(*(const uint16_t*)&hnb);                                            \
    }                                                                                        \
    u32x2 hp;                                                                                \
    hp[0] = hb[0] | (hb[1] << 16);                                                           \
    hp[1] = hb[2] | (hb[3] << 16);                                                           \
    asm volatile("global_store_dwordx2 %0, %1, off sc0 sc1"                                  \
                 :: "v"((PST) + (long)l * 131072), "v"(hp) : "memory");                      \
    asm volatile("s_waitcnt vmcnt(0)" ::: "memory");                                         \
    if (lane == 0)                                                                           \
      __hip_atomic_store(MF, l + 1, __ATOMIC_RELAXED, __HIP_MEMORY_SCOPE_AGENT);             \
  }

__global__ __launch_bounds__(128, 1) void k_gru15(
    const bf16* __restrict__ Whh, const float* __restrict__ bhh,
    const bf16* __restrict__ gi, uint8_t* __restrict__ ys2, int* __restrict__ flags)
{
  __shared__ bf16 lsW[96 * 520];
  const int t = threadIdx.x, lane = t & 63, w = t >> 6;
  const int jcb = blockIdx.x & 15, cpair = blockIdx.x >> 4;
  const int cA = cpair, cB = cpair + 4;
  const int lc = lane & 15, lk = lane >> 4;
  const int cols0 = jcb * 32;
  const int p = jcb * 2 + w;            // producer / d-tile index 0..31
  const int d0 = p * 16 + lk * 4;       // this lane's 4 consecutive d (per group lc)

  // stage W slice (r12 verbatim; shared by both chains)
#pragma unroll
  for (int it = 0; it < 48; ++it) {
    const int c = it * 128 + t;
    const int row = c >> 6, col8 = (c & 63) * 8;
    const int e = ((row >> 5) << 9) + cols0 + (row & 31);
    *(uint4*)&lsW[row * 520 + col8] = *(const uint4*)&Whh[(long)e * 512 + col8];
  }
  __syncthreads();

  float bRa[4], bZa[4], bNa[4];       // biases depend only on d -> shared
#pragma unroll
  for (int j = 0; j < 4; ++j) {
    bRa[j] = bhh[d0 + j];
    bZa[j] = bhh[512 + d0 + j];
    bNa[j] = bhh[1024 + d0 + j];
  }
  float hregA[4] = {0.f, 0.f, 0.f, 0.f};
  float hregB[4] = {0.f, 0.f, 0.f, 0.f};

  const bf16* gpA = gi + (long)(cA * 16 + lc) * 786432 + d0;
  const bf16* gpB = gi + (long)(cB * 16 + lc) * 786432 + d0;
  uint8_t* psA = ys2 + (long)cA * 16384 + p * 512 + lc * 32 + lk * 8;
  uint8_t* psB = ys2 + (long)cB * 16384 + p * 512 + lc * 32 + lk * 8;
  const long laneoff = (long)(lk >> 1) * 512 + lc * 32 + (lk & 1) * 16;

  int* cfA = flags + cA * 32 * 32;
  int* cfB = flags + cB * 32 * 32;
  int* mfA = cfA + p * 32;
  int* mfB = cfB + p * 32;

  for (int l = 0; l < 512; ++l) {
    // both chains' gi loads issued up-front (r8/r12-proven placement); the
    // first vmcnt(0)/poll-wait drains them while flags propagate
    u32x2 gRa, gZa, gNa, gRb, gZb, gNb;
    asm volatile("global_load_dwordx2 %0, %1, off"             : "=v"(gRa) : "v"(gpA) : "memory");
    asm volatile("global_load_dwordx2 %0, %1, off offset:1024" : "=v"(gZa) : "v"(gpA) : "memory");
    asm volatile("global_load_dwordx2 %0, %1, off offset:2048" : "=v"(gNa) : "v"(gpA) : "memory");
    asm volatile("global_load_dwordx2 %0, %1, off"             : "=v"(gRb) : "v"(gpB) : "memory");
    asm volatile("global_load_dwordx2 %0, %1, off offset:1024" : "=v"(gZb) : "v"(gpB) : "memory");
    asm volatile("global_load_dwordx2 %0, %1, off offset:2048" : "=v"(gNb) : "v"(gpB) : "memory");
    gpA += 1536;
    gpB += 1536;

    GRU_PHASE(cA, cfA, mfA, gRa, gZa, gNa, hregA, psA)
    GRU_PHASE(cB, cfB, mfB, gRb, gZb, gNb, hregB, psB)
  }
}
#undef GRU_PHASE

// ---------------- launch ----------------
extern "C" void kernel_launch(void* const* d_in, const int* in_sizes, int n_in,
                              void* d_out, int out_size, void* d_ws, size_t ws_size,
                              hipStream_t stream)
{
  (void)in_sizes; (void)n_in; (void)out_size; (void)ws_size;
  const float* in_feats = (const float*)d_in[0];
  const int*   e_src    = (const int*)d_in[1];
  const int*   e_dst    = (const int*)d_in[2];
  const int*   seq      = (const int*)d_in[3];
  const float* W_conv   = (const float*)d_in[4];
  const float* b_conv   = (const float*)d_in[5];
  const float* W_ff1    = (const float*)d_in[6];
  const float* b_ff1    = (const float*)d_in[7];
  const float* W_ih     = (const float*)d_in[8];
  const float* W_hh     = (const float*)d_in[9];
  const float* b_ih     = (const float*)d_in[10];
  const float* b_hh     = (const float*)d_in[11];
  const float* W_ff2    = (const float*)d_in[12];
  const float* b_ff2    = (const float*)d_in[13];

  uint8_t* ws = (uint8_t*)d_ws;
  int*  deg     = (int*) (ws + 0);
  int*  cursor  = (int*) (ws + 262144u);
  int*  roff    = (int*) (ws + 524288u);
  bf16* WcT     = (bf16*)(ws + 1048576u);
  bf16* Wf1T    = (bf16*)(ws + 1572864u);
  bf16* Wf2T    = (bf16*)(ws + 2097152u);
  bf16* WihB    = (bf16*)(ws + 2621440u);
  bf16* WhhB    = (bf16*)(ws + 4194304u);
  int*  csr     = (int*) (ws + 6291456u);
  int*  flags   = (int*) (ws + 10485760u);     // 8 chains x 32 producers x 128B = 32KB
  int*  partial = (int*) (ws + 10616832u);     // 64 ints
  int*  sbase   = (int*) (ws + 10620928u);     // 65 ints
  bf16* med2    = (bf16*)(ws + 16777216u);     // 67MB; reused as ys2 after gi GEMM
  uint8_t* ys2  = (uint8_t*)med2;              // [l][chain][p][gl][16dl] bf16 = 64MB
  bf16* gib     = (bf16*)(ws + 83886080u);     // 201MB; aggb/med1/featsb live here pre-gi
  bf16* aggb    = (bf16*)(ws + 83886080u);
  bf16* med1    = (bf16*)(ws + 150994944u);    // also featsb (dead before med1 written)
  bf16* featsb  = (bf16*)(ws + 150994944u);

  hipMemsetAsync(deg,   0, NN * 4,          stream);
  hipMemsetAsync(flags, 0, 8 * 32 * 32 * 4, stream);

  k_prep <<<3072, 256, 0, stream>>>(W_conv, W_ff1, W_ff2, W_ih, W_hh, WcT, Wf1T, Wf2T, WihB, WhhB);
  k_cast <<<NN * DD / 1024, 256, 0, stream>>>(in_feats, featsb);
  k_deg  <<<EE / 256, 256, 0, stream>>>(e_dst, deg);
  k_scan1<<<64, 1024, 0, stream>>>(deg, roff, partial);
  k_scan2<<<1, 64, 0, stream>>>(partial, sbase);
  k_scan3<<<64, 1024, 0, stream>>>(sbase, roff, cursor);
  k_fill <<<EE / 256, 256, 0, stream>>>(e_src, e_dst, cursor, csr);
  k_agg  <<<NN, 128, 0, stream>>>(featsb, csr, roff, aggb);

  dim3 g512(4, 512), g1536(12, 512);
  k_gemm<false, false><<<g512,  256, 0, stream>>>(aggb, WcT,  b_conv, nullptr, med1, 512);
  k_gemm<false, true ><<<g512,  256, 0, stream>>>(med1, Wf1T, b_ff1,  nullptr, med2, 512);
  k_gemm<true,  false><<<g1536, 256, 0, stream>>>(med2, WihB, b_ih,   seq,     gib,  1536);

  k_gru15<<<64, 128, 0, stream>>>(WhhB, b_hh, gib, ys2, flags);

  k_gemm_ys<<<g512, 256, 0, stream>>>(ys2, Wf2T, b_ff2, seq, (float*)d_out);
}

// Round 16
// 2430.735 us; speedup vs baseline: 1.3059x; 1.3059x over previous
//
#include <hip/hip_runtime.h>
#include <hip/hip_bf16.h>
#include <stdint.h>

typedef __hip_bfloat16 bf16;
typedef __attribute__((ext_vector_type(8))) short short8;
typedef __attribute__((ext_vector_type(4))) float f32x4;
typedef __attribute__((ext_vector_type(4))) unsigned int u32x4;
typedef __attribute__((ext_vector_type(2))) unsigned int u32x2;

#define NN 65536
#define DD 512
#define EE 1048576
#define GG 128
#define LL 512

static __device__ __forceinline__ void gld_lds16(const void* g, void* l) {
  __builtin_amdgcn_global_load_lds((const __attribute__((address_space(1))) uint32_t*)g,
                                   (__attribute__((address_space(3))) uint32_t*)l, 16, 0, 0);
}

// ---------------- prep: transpose/cast weights to bf16 ----------------
__global__ __launch_bounds__(256) void k_prep(
    const float* __restrict__ Wc, const float* __restrict__ Wf1, const float* __restrict__ Wf2,
    const float* __restrict__ Wih, const float* __restrict__ Whh,
    bf16* __restrict__ WcT, bf16* __restrict__ Wf1T, bf16* __restrict__ Wf2T,
    bf16* __restrict__ WihB, bf16* __restrict__ WhhB)
{
  const int i = blockIdx.x * 256 + threadIdx.x;
  if (i < 512 * 512) {
    const int k = i >> 9, n = i & 511;
    WcT [n * 512 + k] = __float2bfloat16(Wc [i]);
    Wf1T[n * 512 + k] = __float2bfloat16(Wf1[i]);
    Wf2T[n * 512 + k] = __float2bfloat16(Wf2[i]);
  }
  if (i < 1536 * 512) {
    WihB[i] = __float2bfloat16(Wih[i]);
    WhhB[i] = __float2bfloat16(Whh[i]);
  }
}

// ---------------- cast node features to bf16 ----------------
__global__ __launch_bounds__(256) void k_cast(const float* __restrict__ f, bf16* __restrict__ o) {
  const long i = (long)(blockIdx.x * 256 + threadIdx.x) * 4;
  const float4 v = *(const float4*)&f[i];
  union { bf16 b[4]; ushort4 u; } pk;
  pk.b[0] = __float2bfloat16(v.x);
  pk.b[1] = __float2bfloat16(v.y);
  pk.b[2] = __float2bfloat16(v.z);
  pk.b[3] = __float2bfloat16(v.w);
  *(ushort4*)&o[i] = pk.u;
}

// ---------------- CSR build ----------------
__global__ __launch_bounds__(256) void k_deg(const int* __restrict__ dst, int* __restrict__ deg) {
  const int e = blockIdx.x * 256 + threadIdx.x;
  atomicAdd(&deg[dst[e]], 1);
}

__global__ __launch_bounds__(1024) void k_scan1(const int* __restrict__ deg,
                                                int* __restrict__ roff, int* __restrict__ partial) {
  __shared__ int sd[1024];
  const int t = threadIdx.x, b = blockIdx.x, i = b * 1024 + t;
  const int v = deg[i];
  sd[t] = v;
  __syncthreads();
  for (int off = 1; off < 1024; off <<= 1) {
    int add = (t >= off) ? sd[t - off] : 0;
    __syncthreads();
    sd[t] += add;
    __syncthreads();
  }
  roff[i] = sd[t] - v;
  if (t == 1023) partial[b] = sd[t];
}

__global__ __launch_bounds__(64) void k_scan2(const int* __restrict__ partial, int* __restrict__ base) {
  __shared__ int sd[64];
  const int t = threadIdx.x;
  const int v = partial[t];
  sd[t] = v;
  __syncthreads();
  for (int off = 1; off < 64; off <<= 1) {
    int add = (t >= off) ? sd[t - off] : 0;
    __syncthreads();
    sd[t] += add;
    __syncthreads();
  }
  base[t] = sd[t] - v;
  if (t == 63) base[64] = sd[63];
}

__global__ __launch_bounds__(1024) void k_scan3(const int* __restrict__ base,
                                                int* __restrict__ roff, int* __restrict__ cursor) {
  const int b = blockIdx.x, t = threadIdx.x, i = b * 1024 + t;
  const int v = roff[i] + base[b];
  roff[i] = v;
  cursor[i] = v;
  if (i == 0) roff[NN] = base[64];
}

__global__ __launch_bounds__(256) void k_fill(const int* __restrict__ src, const int* __restrict__ dst,
                                              int* __restrict__ cursor, int* __restrict__ csr) {
  const int e = blockIdx.x * 256 + threadIdx.x;
  const int p = atomicAdd(&cursor[dst[e]], 1);
  csr[p] = src[e];
}

// ---------------- mean aggregation (bf16 gather, fp32 accum, 4-wide ILP) ----------------
__global__ __launch_bounds__(128) void k_agg(
    const bf16* __restrict__ featsb, const int* __restrict__ csr,
    const int* __restrict__ roff, bf16* __restrict__ agg)
{
  const int n = blockIdx.x, t = threadIdx.x;
  const int s0 = roff[n], s1 = roff[n + 1];
  float a0 = 0.f, a1 = 0.f, a2 = 0.f, a3 = 0.f;
  int i = s0;
  for (; i + 4 <= s1; i += 4) {
    const int sA = csr[i], sB = csr[i + 1], sC = csr[i + 2], sD = csr[i + 3];
    const ushort4 vA = *(const ushort4*)&featsb[(long)sA * 512 + t * 4];
    const ushort4 vB = *(const ushort4*)&featsb[(long)sB * 512 + t * 4];
    const ushort4 vC = *(const ushort4*)&featsb[(long)sC * 512 + t * 4];
    const ushort4 vD = *(const ushort4*)&featsb[(long)sD * 512 + t * 4];
    union { uint32_t u; float f; } c;
    c.u = (uint32_t)vA.x << 16; a0 += c.f;  c.u = (uint32_t)vA.y << 16; a1 += c.f;
    c.u = (uint32_t)vA.z << 16; a2 += c.f;  c.u = (uint32_t)vA.w << 16; a3 += c.f;
    c.u = (uint32_t)vB.x << 16; a0 += c.f;  c.u = (uint32_t)vB.y << 16; a1 += c.f;
    c.u = (uint32_t)vB.z << 16; a2 += c.f;  c.u = (uint32_t)vB.w << 16; a3 += c.f;
    c.u = (uint32_t)vC.x << 16; a0 += c.f;  c.u = (uint32_t)vC.y << 16; a1 += c.f;
    c.u = (uint32_t)vC.z << 16; a2 += c.f;  c.u = (uint32_t)vC.w << 16; a3 += c.f;
    c.u = (uint32_t)vD.x << 16; a0 += c.f;  c.u = (uint32_t)vD.y << 16; a1 += c.f;
    c.u = (uint32_t)vD.z << 16; a2 += c.f;  c.u = (uint32_t)vD.w << 16; a3 += c.f;
  }
  for (; i < s1; ++i) {
    const int s = csr[i];
    const ushort4 v = *(const ushort4*)&featsb[(long)s * 512 + t * 4];
    union { uint32_t u; float f; } c;
    c.u = (uint32_t)v.x << 16; a0 += c.f;  c.u = (uint32_t)v.y << 16; a1 += c.f;
    c.u = (uint32_t)v.z << 16; a2 += c.f;  c.u = (uint32_t)v.w << 16; a3 += c.f;
  }
  const float sc = 1.f / fmaxf((float)(s1 - s0), 1.f);
  union { bf16 b[4]; ushort4 u; } pk;
  pk.b[0] = __float2bfloat16(a0 * sc);
  pk.b[1] = __float2bfloat16(a1 * sc);
  pk.b[2] = __float2bfloat16(a2 * sc);
  pk.b[3] = __float2bfloat16(a3 * sc);
  *(ushort4*)&agg[(long)n * 512 + t * 4] = pk.u;
}

// ---------------- bf16 GEMM: C[M,Ncols] = A[M,512] @ Bt[Ncols,512]^T + bias ----------------
template<bool GATHER, bool RELU>
__global__ __launch_bounds__(256) void k_gemm(
    const bf16* __restrict__ A, const bf16* __restrict__ Bt,
    const float* __restrict__ bias, const int* __restrict__ gidx,
    bf16* __restrict__ outb, int Ncols)
{
  __shared__ bf16 lsA[128 * 64];
  __shared__ bf16 lsB[128 * 64];
  const int t = threadIdx.x;
  const int lane = t & 63, wid = t >> 6;
  const int wr = wid >> 1, wc = wid & 1;
  const int tm = blockIdx.y * 128, tn = blockIdx.x * 128;
  const int col8 = (t & 7) * 8;
  const int rsub = t >> 3;
  const int lc = lane & 15, lk = lane >> 4;

  long arow[4], brow[4];
#pragma unroll
  for (int i = 0; i < 4; ++i) {
    const int r = tm + i * 32 + rsub;
    int ar = r;
    if constexpr (GATHER) ar = gidx[r];
    arow[i] = (long)ar * 512;
    brow[i] = (long)(tn + i * 32 + rsub) * 512;
  }

  f32x4 acc[4][4];
#pragma unroll
  for (int a = 0; a < 4; ++a)
#pragma unroll
    for (int b = 0; b < 4; ++b) acc[a][b] = (f32x4){0.f, 0.f, 0.f, 0.f};

  for (int ks = 0; ks < 8; ++ks) {
    const int k0 = ks * 64;
#pragma unroll
    for (int i = 0; i < 4; ++i) {
      gld_lds16(A  + arow[i] + k0 + col8, &lsA[i * 2048 + t * 8]);
      gld_lds16(Bt + brow[i] + k0 + col8, &lsB[i * 2048 + t * 8]);
    }
    __syncthreads();
#pragma unroll
    for (int kk = 0; kk < 2; ++kk) {
      short8 af[4], bfr[4];
#pragma unroll
      for (int mi = 0; mi < 4; ++mi)
        af[mi] = *(const short8*)&lsA[(wr * 64 + mi * 16 + lc) * 64 + kk * 32 + lk * 8];
#pragma unroll
      for (int ni = 0; ni < 4; ++ni)
        bfr[ni] = *(const short8*)&lsB[(wc * 64 + ni * 16 + lc) * 64 + kk * 32 + lk * 8];
#pragma unroll
      for (int mi = 0; mi < 4; ++mi)
#pragma unroll
        for (int ni = 0; ni < 4; ++ni)
          acc[mi][ni] = __builtin_amdgcn_mfma_f32_16x16x32_bf16(af[mi], bfr[ni], acc[mi][ni], 0, 0, 0);
    }
    __syncthreads();
  }

  float bv[4];
#pragma unroll
  for (int ni = 0; ni < 4; ++ni) bv[ni] = bias[tn + wc * 64 + ni * 16 + lc];

#pragma unroll
  for (int mi = 0; mi < 4; ++mi) {
    const int r0 = tm + wr * 64 + mi * 16 + lk * 4;
#pragma unroll
    for (int j = 0; j < 4; ++j) {
      const int row = r0 + j;
      const long orow = (long)row * Ncols;
#pragma unroll
      for (int ni = 0; ni < 4; ++ni) {
        float v = acc[mi][ni][j] + bv[ni];
        if constexpr (RELU) v = fmaxf(v, 0.f);
        const int c = tn + wc * 64 + ni * 16 + lc;
        outb[orow + c] = __float2bfloat16(v);
      }
    }
  }
}

// ---------------- ff2 GEMM reading ys2 layout, scatter output ----------------
// ys2 element (g,l,k):  byte = ((l*8 + (g>>4))*32 + (k>>4))*512 + (g&15)*32 + (k&15)*2
__global__ __launch_bounds__(256) void k_gemm_ys(
    const uint8_t* __restrict__ Ay, const bf16* __restrict__ Bt,
    const float* __restrict__ bias, const int* __restrict__ gidx,
    float* __restrict__ outf)
{
  __shared__ bf16 lsA[128 * 64];
  __shared__ bf16 lsB[128 * 64];
  const int t = threadIdx.x;
  const int lane = t & 63, wid = t >> 6;
  const int wr = wid >> 1, wc = wid & 1;
  const int tm = blockIdx.y * 128, tn = blockIdx.x * 128;
  const int col8 = (t & 7) * 8;
  const int rsub = t >> 3;
  const int lc = lane & 15, lk = lane >> 4;

  long arow[4], brow[4];
#pragma unroll
  for (int i = 0; i < 4; ++i) {
    const int r = tm + i * 32 + rsub;
    const int g = r >> 9, l = r & 511;
    arow[i] = ((long)l * 8 + (g >> 4)) * 16384 + (g & 15) * 32;
    brow[i] = (long)(tn + i * 32 + rsub) * 512;
  }

  f32x4 acc[4][4];
#pragma unroll
  for (int a = 0; a < 4; ++a)
#pragma unroll
    for (int b = 0; b < 4; ++b) acc[a][b] = (f32x4){0.f, 0.f, 0.f, 0.f};

  for (int ks = 0; ks < 8; ++ks) {
    const int k0 = ks * 64;
    const int kk16 = k0 + col8;
    const long aoff = ((long)(kk16 >> 4) << 9) + ((kk16 & 15) << 1);
#pragma unroll
    for (int i = 0; i < 4; ++i) {
      gld_lds16(Ay + arow[i] + aoff, &lsA[i * 2048 + t * 8]);
      gld_lds16(Bt + brow[i] + k0 + col8, &lsB[i * 2048 + t * 8]);
    }
    __syncthreads();
#pragma unroll
    for (int kk = 0; kk < 2; ++kk) {
      short8 af[4], bfr[4];
#pragma unroll
      for (int mi = 0; mi < 4; ++mi)
        af[mi] = *(const short8*)&lsA[(wr * 64 + mi * 16 + lc) * 64 + kk * 32 + lk * 8];
#pragma unroll
      for (int ni = 0; ni < 4; ++ni)
        bfr[ni] = *(const short8*)&lsB[(wc * 64 + ni * 16 + lc) * 64 + kk * 32 + lk * 8];
#pragma unroll
      for (int mi = 0; mi < 4; ++mi)
#pragma unroll
        for (int ni = 0; ni < 4; ++ni)
          acc[mi][ni] = __builtin_amdgcn_mfma_f32_16x16x32_bf16(af[mi], bfr[ni], acc[mi][ni], 0, 0, 0);
    }
    __syncthreads();
  }

  float bv[4];
#pragma unroll
  for (int ni = 0; ni < 4; ++ni) bv[ni] = bias[tn + wc * 64 + ni * 16 + lc];

#pragma unroll
  for (int mi = 0; mi < 4; ++mi) {
    const int r0 = tm + wr * 64 + mi * 16 + lk * 4;
#pragma unroll
    for (int j = 0; j < 4; ++j) {
      const int row = r0 + j;
      const long orow = (long)gidx[row] * 512;
#pragma unroll
      for (int ni = 0; ni < 4; ++ni) {
        const int c = tn + wc * 64 + ni * 16 + lc;
        outf[orow + c] = acc[mi][ni][j] + bv[ni];
      }
    }
  }
}

// ---------------- persistent GRU v16: r12 protocol at AGENT scope ----------------
// Byte-identical to r12 (best: 1710us) EXCEPT the h-exchange data ops use
// agent/device scope (sc1) instead of system scope (sc0 sc1). SC[1:0]:
// 0b10=agent (MALL-coherent, all XCDs) vs 0b11=system (host-coherent,
// deeper ack point / stricter serialization). Agent scope is sufficient
// (single-GPU exchange) and is correctness-PROVEN here: the flag stamps and
// polls have been agent-scope (__hip_atomic RELAXED AGENT -> sc1) in every
// passing round, and r3's h-loads were agent-scope atomics with correct
// results. Hypothesis: system-scope per-op cost is the 2-3x inflation of
// every coherent hop (store-drain ack + h-load RTT) in the step chain.
__global__ __launch_bounds__(128, 1) void k_gru16(
    const bf16* __restrict__ Whh, const float* __restrict__ bhh,
    const bf16* __restrict__ gi, uint8_t* __restrict__ ys2, int* __restrict__ flags)
{
  __shared__ bf16 lsW[96 * 520];
  const int t = threadIdx.x, lane = t & 63, w = t >> 6;
  const int chain = blockIdx.x >> 4, jcb = blockIdx.x & 15;
  const int lc = lane & 15, lk = lane >> 4;
  const int g0 = chain * 16;
  const int cols0 = jcb * 32;
  const int p = jcb * 2 + w;            // producer / d-tile index 0..31
  const int d0 = p * 16 + lk * 4;       // this lane's 4 consecutive d (group lc)

  // stage W slice (proven layout)
#pragma unroll
  for (int it = 0; it < 48; ++it) {
    const int c = it * 128 + t;
    const int row = c >> 6, col8 = (c & 63) * 8;
    const int e = ((row >> 5) << 9) + cols0 + (row & 31);
    *(uint4*)&lsW[row * 520 + col8] = *(const uint4*)&Whh[(long)e * 512 + col8];
  }
  __syncthreads();

  float bRa[4], bZa[4], bNa[4];
#pragma unroll
  for (int j = 0; j < 4; ++j) {
    bRa[j] = bhh[d0 + j];
    bZa[j] = bhh[512 + d0 + j];
    bNa[j] = bhh[1024 + d0 + j];
  }
  float hreg[4] = {0.f, 0.f, 0.f, 0.f};

  // gi: lane covers (group g0+lc, gates at +0/+512/+1024 elems, d = d0..d0+3)
  const bf16* gp = gi + (long)(g0 + lc) * 786432 + d0;
  // producer store base (bytes): ys2[l][chain][p][gl=lc][dl=lk*4]
  uint8_t* psto = ys2 + (long)chain * 16384 + p * 512 + lc * 32 + lk * 8;
  // consumer lane offset (bytes) within a (l,chain) slab
  const long laneoff = (long)(lk >> 1) * 512 + lc * 32 + (lk & 1) * 16;

  int* chflags = flags + chain * 32 * 32;      // 32 producers x 128B stride
  int* myflag  = chflags + p * 32;

  for (int l = 0; l < 512; ++l) {
    // gi dwordx2 loads issued BEFORE the poll (r8/r12-proven placement)
    u32x2 gRv, gZv, gNv;
    asm volatile("global_load_dwordx2 %0, %1, off"             : "=v"(gRv) : "v"(gp) : "memory");
    asm volatile("global_load_dwordx2 %0, %1, off offset:1024" : "=v"(gZv) : "v"(gp) : "memory");
    asm volatile("global_load_dwordx2 %0, %1, off offset:2048" : "=v"(gNv) : "v"(gp) : "memory");
    gp += 1536;

    f32x4 acc[3] = { (f32x4){0.f,0.f,0.f,0.f}, (f32x4){0.f,0.f,0.f,0.f}, (f32x4){0.f,0.f,0.f,0.f} };
    if (l > 0) {
      // wait for all 32 producers of this chain to stamp step l
      int ok;
      do {
        const int v = __hip_atomic_load(&chflags[(lane & 31) * 32], __ATOMIC_RELAXED,
                                        __HIP_MEMORY_SCOPE_AGENT);
        ok = __all(v >= l);
      } while (!ok);
      asm volatile("" ::: "memory");

      // h_{l-1} = ys2[l-1][chain]: 16 pipelined 16B loads, AGENT scope (sc1)
      const uint8_t* pb = ys2 + ((long)(l - 1) * 8 + chain) * 16384 + laneoff;
      u32x4 hv[16];
#pragma unroll
      for (int q = 0; q < 4; ++q) {
        const uint8_t* pbq = pb + q * 4096;
#pragma unroll
        for (int r2 = 0; r2 < 4; ++r2)
          asm volatile("global_load_dwordx4 %0, %1, off offset:%2 sc1"
                       : "=v"(hv[q * 4 + r2]) : "v"(pbq), "n"(r2 * 1024) : "memory");
      }
      asm volatile("s_waitcnt vmcnt(0)" ::: "memory");
      __builtin_amdgcn_sched_barrier(0);

#pragma unroll
      for (int kk = 0; kk < 16; ++kk) {
        union { u32x4 u; short8 s; } cv;
        cv.u = hv[kk];
#pragma unroll
        for (int gate = 0; gate < 3; ++gate) {
          const short8 wfr = *(const short8*)&lsW[(gate * 32 + w * 16 + lc) * 520 + kk * 32 + lk * 8];
          acc[gate] = __builtin_amdgcn_mfma_f32_16x16x32_bf16(wfr, cv.s, acc[gate], 0, 0, 0);
        }
      }
    } else {
      asm volatile("s_waitcnt vmcnt(0)" ::: "memory");
      __builtin_amdgcn_sched_barrier(0);
    }

    uint32_t hb[4];
#pragma unroll
    for (int j = 0; j < 4; ++j) {
      const uint32_t sh = (j & 1) * 16;
      union { uint32_t u; float f; } cR, cZ, cN;
      cR.u = ((gRv[j >> 1] >> sh) & 0xffffu) << 16;
      cZ.u = ((gZv[j >> 1] >> sh) & 0xffffu) << 16;
      cN.u = ((gNv[j >> 1] >> sh) & 0xffffu) << 16;
      const float r = 1.f / (1.f + __expf(-(cR.f + acc[0][j] + bRa[j])));
      const float z = 1.f / (1.f + __expf(-(cZ.f + acc[1][j] + bZa[j])));
      const float x2 = cN.f + r * (acc[2][j] + bNa[j]);
      const float ex = __expf(2.f * x2);
      const float n = 1.f - 2.f / (ex + 1.f);          // tanh
      const float hn = (1.f - z) * n + z * hreg[j];
      hreg[j] = hn;
      const bf16 hnb = __float2bfloat16(hn);
      hb[j] = (uint32_t)(*(const uint16_t*)&hnb);
    }
    u32x2 hp;
    hp[0] = hb[0] | (hb[1] << 16);
    hp[1] = hb[2] | (hb[3] << 16);
    // AGENT-scope store (sc1): write-through to MALL (device coherence point)
    asm volatile("global_store_dwordx2 %0, %1, off sc1" :: "v"(psto), "v"(hp) : "memory");
    psto += 131072;                                     // next l-slab (8*16384 B)
    asm volatile("s_waitcnt vmcnt(0)" ::: "memory");    // drain the single h store
    if (lane == 0)
      __hip_atomic_store(myflag, l + 1, __ATOMIC_RELAXED, __HIP_MEMORY_SCOPE_AGENT);
  }
}

// ---------------- launch ----------------
extern "C" void kernel_launch(void* const* d_in, const int* in_sizes, int n_in,
                              void* d_out, int out_size, void* d_ws, size_t ws_size,
                              hipStream_t stream)
{
  (void)in_sizes; (void)n_in; (void)out_size; (void)ws_size;
  const float* in_feats = (const float*)d_in[0];
  const int*   e_src    = (const int*)d_in[1];
  const int*   e_dst    = (const int*)d_in[2];
  const int*   seq      = (const int*)d_in[3];
  const float* W_conv   = (const float*)d_in[4];
  const float* b_conv   = (const float*)d_in[5];
  const float* W_ff1    = (const float*)d_in[6];
  const float* b_ff1    = (const float*)d_in[7];
  const float* W_ih     = (const float*)d_in[8];
  const float* W_hh     = (const float*)d_in[9];
  const float* b_ih     = (const float*)d_in[10];
  const float* b_hh     = (const float*)d_in[11];
  const float* W_ff2    = (const float*)d_in[12];
  const float* b_ff2    = (const float*)d_in[13];

  uint8_t* ws = (uint8_t*)d_ws;
  int*  deg     = (int*) (ws + 0);
  int*  cursor  = (int*) (ws + 262144u);
  int*  roff    = (int*) (ws + 524288u);
  bf16* WcT     = (bf16*)(ws + 1048576u);
  bf16* Wf1T    = (bf16*)(ws + 1572864u);
  bf16* Wf2T    = (bf16*)(ws + 2097152u);
  bf16* WihB    = (bf16*)(ws + 2621440u);
  bf16* WhhB    = (bf16*)(ws + 4194304u);
  int*  csr     = (int*) (ws + 6291456u);
  int*  flags   = (int*) (ws + 10485760u);     // 8 chains x 32 producers x 128B = 32KB
  int*  partial = (int*) (ws + 10616832u);     // 64 ints
  int*  sbase   = (int*) (ws + 10620928u);     // 65 ints
  bf16* med2    = (bf16*)(ws + 16777216u);     // 67MB; reused as ys2 after gi GEMM
  uint8_t* ys2  = (uint8_t*)med2;              // [l][chain][p][gl][16dl] bf16 = 64MB
  bf16* gib     = (bf16*)(ws + 83886080u);     // 201MB; aggb/med1/featsb live here pre-gi
  bf16* aggb    = (bf16*)(ws + 83886080u);
  bf16* med1    = (bf16*)(ws + 150994944u);    // also featsb (dead before med1 written)
  bf16* featsb  = (bf16*)(ws + 150994944u);

  hipMemsetAsync(deg,   0, NN * 4,          stream);
  hipMemsetAsync(flags, 0, 8 * 32 * 32 * 4, stream);

  k_prep <<<3072, 256, 0, stream>>>(W_conv, W_ff1, W_ff2, W_ih, W_hh, WcT, Wf1T, Wf2T, WihB, WhhB);
  k_cast <<<NN * DD / 1024, 256, 0, stream>>>(in_feats, featsb);
  k_deg  <<<EE / 256, 256, 0, stream>>>(e_dst, deg);
  k_scan1<<<64, 1024, 0, stream>>>(deg, roff, partial);
  k_scan2<<<1, 64, 0, stream>>>(partial, sbase);
  k_scan3<<<64, 1024, 0, stream>>>(sbase, roff, cursor);
  k_fill <<<EE / 256, 256, 0, stream>>>(e_src, e_dst, cursor, csr);
  k_agg  <<<NN, 128, 0, stream>>>(featsb, csr, roff, aggb);

  dim3 g512(4, 512), g1536(12, 512);
  k_gemm<false, false><<<g512,  256, 0, stream>>>(aggb, WcT,  b_conv, nullptr, med1, 512);
  k_gemm<false, true ><<<g512,  256, 0, stream>>>(med1, Wf1T, b_ff1,  nullptr, med2, 512);
  k_gemm<true,  false><<<g1536, 256, 0, stream>>>(med2, WihB, b_ih,   seq,     gib,  1536);

  k_gru16<<<128, 128, 0, stream>>>(WhhB, b_hh, gib, ys2, flags);

  k_gemm_ys<<<g512, 256, 0, stream>>>(ys2, Wf2T, b_ff2, seq, (float*)d_out);
}

// Round 18
// 2428.867 us; speedup vs baseline: 1.3069x; 1.0008x over previous
//
#include <hip/hip_runtime.h>
#include <hip/hip_bf16.h>
#include <stdint.h>

typedef __hip_bfloat16 bf16;
typedef __attribute__((ext_vector_type(8))) short short8;
typedef __attribute__((ext_vector_type(4))) float f32x4;
typedef __attribute__((ext_vector_type(4))) unsigned int u32x4;
typedef __attribute__((ext_vector_type(2))) unsigned int u32x2;

#define NN 65536
#define DD 512
#define EE 1048576
#define GG 128
#define LL 512

static __device__ __forceinline__ void gld_lds16(const void* g, void* l) {
  __builtin_amdgcn_global_load_lds((const __attribute__((address_space(1))) uint32_t*)g,
                                   (__attribute__((address_space(3))) uint32_t*)l, 16, 0, 0);
}

// ---------------- prep: transpose/cast weights to bf16 ----------------
__global__ __launch_bounds__(256) void k_prep(
    const float* __restrict__ Wc, const float* __restrict__ Wf1, const float* __restrict__ Wf2,
    const float* __restrict__ Wih, const float* __restrict__ Whh,
    bf16* __restrict__ WcT, bf16* __restrict__ Wf1T, bf16* __restrict__ Wf2T,
    bf16* __restrict__ WihB, bf16* __restrict__ WhhB)
{
  const int i = blockIdx.x * 256 + threadIdx.x;
  if (i < 512 * 512) {
    const int k = i >> 9, n = i & 511;
    WcT [n * 512 + k] = __float2bfloat16(Wc [i]);
    Wf1T[n * 512 + k] = __float2bfloat16(Wf1[i]);
    Wf2T[n * 512 + k] = __float2bfloat16(Wf2[i]);
  }
  if (i < 1536 * 512) {
    WihB[i] = __float2bfloat16(Wih[i]);
    WhhB[i] = __float2bfloat16(Whh[i]);
  }
}

// ---------------- cast node features to bf16 ----------------
__global__ __launch_bounds__(256) void k_cast(const float* __restrict__ f, bf16* __restrict__ o) {
  const long i = (long)(blockIdx.x * 256 + threadIdx.x) * 4;
  const float4 v = *(const float4*)&f[i];
  union { bf16 b[4]; ushort4 u; } pk;
  pk.b[0] = __float2bfloat16(v.x);
  pk.b[1] = __float2bfloat16(v.y);
  pk.b[2] = __float2bfloat16(v.z);
  pk.b[3] = __float2bfloat16(v.w);
  *(ushort4*)&o[i] = pk.u;
}

// ---------------- CSR build ----------------
__global__ __launch_bounds__(256) void k_deg(const int* __restrict__ dst, int* __restrict__ deg) {
  const int e = blockIdx.x * 256 + threadIdx.x;
  atomicAdd(&deg[dst[e]], 1);
}

__global__ __launch_bounds__(1024) void k_scan1(const int* __restrict__ deg,
                                                int* __restrict__ roff, int* __restrict__ partial) {
  __shared__ int sd[1024];
  const int t = threadIdx.x, b = blockIdx.x, i = b * 1024 + t;
  const int v = deg[i];
  sd[t] = v;
  __syncthreads();
  for (int off = 1; off < 1024; off <<= 1) {
    int add = (t >= off) ? sd[t - off] : 0;
    __syncthreads();
    sd[t] += add;
    __syncthreads();
  }
  roff[i] = sd[t] - v;
  if (t == 1023) partial[b] = sd[t];
}

__global__ __launch_bounds__(64) void k_scan2(const int* __restrict__ partial, int* __restrict__ base) {
  __shared__ int sd[64];
  const int t = threadIdx.x;
  const int v = partial[t];
  sd[t] = v;
  __syncthreads();
  for (int off = 1; off < 64; off <<= 1) {
    int add = (t >= off) ? sd[t - off] : 0;
    __syncthreads();
    sd[t] += add;
    __syncthreads();
  }
  base[t] = sd[t] - v;
  if (t == 63) base[64] = sd[63];
}

__global__ __launch_bounds__(1024) void k_scan3(const int* __restrict__ base,
                                                int* __restrict__ roff, int* __restrict__ cursor) {
  const int b = blockIdx.x, t = threadIdx.x, i = b * 1024 + t;
  const int v = roff[i] + base[b];
  roff[i] = v;
  cursor[i] = v;
  if (i == 0) roff[NN] = base[64];
}

__global__ __launch_bounds__(256) void k_fill(const int* __restrict__ src, const int* __restrict__ dst,
                                              int* __restrict__ cursor, int* __restrict__ csr) {
  const int e = blockIdx.x * 256 + threadIdx.x;
  const int p = atomicAdd(&cursor[dst[e]], 1);
  csr[p] = src[e];
}

// ---------------- mean aggregation (bf16 gather, fp32 accum, 4-wide ILP) ----------------
__global__ __launch_bounds__(128) void k_agg(
    const bf16* __restrict__ featsb, const int* __restrict__ csr,
    const int* __restrict__ roff, bf16* __restrict__ agg)
{
  const int n = blockIdx.x, t = threadIdx.x;
  const int s0 = roff[n], s1 = roff[n + 1];
  float a0 = 0.f, a1 = 0.f, a2 = 0.f, a3 = 0.f;
  int i = s0;
  for (; i + 4 <= s1; i += 4) {
    const int sA = csr[i], sB = csr[i + 1], sC = csr[i + 2], sD = csr[i + 3];
    const ushort4 vA = *(const ushort4*)&featsb[(long)sA * 512 + t * 4];
    const ushort4 vB = *(const ushort4*)&featsb[(long)sB * 512 + t * 4];
    const ushort4 vC = *(const ushort4*)&featsb[(long)sC * 512 + t * 4];
    const ushort4 vD = *(const ushort4*)&featsb[(long)sD * 512 + t * 4];
    union { uint32_t u; float f; } c;
    c.u = (uint32_t)vA.x << 16; a0 += c.f;  c.u = (uint32_t)vA.y << 16; a1 += c.f;
    c.u = (uint32_t)vA.z << 16; a2 += c.f;  c.u = (uint32_t)vA.w << 16; a3 += c.f;
    c.u = (uint32_t)vB.x << 16; a0 += c.f;  c.u = (uint32_t)vB.y << 16; a1 += c.f;
    c.u = (uint32_t)vB.z << 16; a2 += c.f;  c.u = (uint32_t)vB.w << 16; a3 += c.f;
    c.u = (uint32_t)vC.x << 16; a0 += c.f;  c.u = (uint32_t)vC.y << 16; a1 += c.f;
    c.u = (uint32_t)vC.z << 16; a2 += c.f;  c.u = (uint32_t)vC.w << 16; a3 += c.f;
    c.u = (uint32_t)vD.x << 16; a0 += c.f;  c.u = (uint32_t)vD.y << 16; a1 += c.f;
    c.u = (uint32_t)vD.z << 16; a2 += c.f;  c.u = (uint32_t)vD.w << 16; a3 += c.f;
  }
  for (; i < s1; ++i) {
    const int s = csr[i];
    const ushort4 v = *(const ushort4*)&featsb[(long)s * 512 + t * 4];
    union { uint32_t u; float f; } c;
    c.u = (uint32_t)v.x << 16; a0 += c.f;  c.u = (uint32_t)v.y << 16; a1 += c.f;
    c.u = (uint32_t)v.z << 16; a2 += c.f;  c.u = (uint32_t)v.w << 16; a3 += c.f;
  }
  const float sc = 1.f / fmaxf((float)(s1 - s0), 1.f);
  union { bf16 b[4]; ushort4 u; } pk;
  pk.b[0] = __float2bfloat16(a0 * sc);
  pk.b[1] = __float2bfloat16(a1 * sc);
  pk.b[2] = __float2bfloat16(a2 * sc);
  pk.b[3] = __float2bfloat16(a3 * sc);
  *(ushort4*)&agg[(long)n * 512 + t * 4] = pk.u;
}

// ---------------- bf16 GEMM: C[M,Ncols] = A[M,512] @ Bt[Ncols,512]^T + bias ----------------
template<bool GATHER, bool RELU>
__global__ __launch_bounds__(256) void k_gemm(
    const bf16* __restrict__ A, const bf16* __restrict__ Bt,
    const float* __restrict__ bias, const int* __restrict__ gidx,
    bf16* __restrict__ outb, int Ncols)
{
  __shared__ bf16 lsA[128 * 64];
  __shared__ bf16 lsB[128 * 64];
  const int t = threadIdx.x;
  const int lane = t & 63, wid = t >> 6;
  const int wr = wid >> 1, wc = wid & 1;
  const int tm = blockIdx.y * 128, tn = blockIdx.x * 128;
  const int col8 = (t & 7) * 8;
  const int rsub = t >> 3;
  const int lc = lane & 15, lk = lane >> 4;

  long arow[4], brow[4];
#pragma unroll
  for (int i = 0; i < 4; ++i) {
    const int r = tm + i * 32 + rsub;
    int ar = r;
    if constexpr (GATHER) ar = gidx[r];
    arow[i] = (long)ar * 512;
    brow[i] = (long)(tn + i * 32 + rsub) * 512;
  }

  f32x4 acc[4][4];
#pragma unroll
  for (int a = 0; a < 4; ++a)
#pragma unroll
    for (int b = 0; b < 4; ++b) acc[a][b] = (f32x4){0.f, 0.f, 0.f, 0.f};

  for (int ks = 0; ks < 8; ++ks) {
    const int k0 = ks * 64;
#pragma unroll
    for (int i = 0; i < 4; ++i) {
      gld_lds16(A  + arow[i] + k0 + col8, &lsA[i * 2048 + t * 8]);
      gld_lds16(Bt + brow[i] + k0 + col8, &lsB[i * 2048 + t * 8]);
    }
    __syncthreads();
#pragma unroll
    for (int kk = 0; kk < 2; ++kk) {
      short8 af[4], bfr[4];
#pragma unroll
      for (int mi = 0; mi < 4; ++mi)
        af[mi] = *(const short8*)&lsA[(wr * 64 + mi * 16 + lc) * 64 + kk * 32 + lk * 8];
#pragma unroll
      for (int ni = 0; ni < 4; ++ni)
        bfr[ni] = *(const short8*)&lsB[(wc * 64 + ni * 16 + lc) * 64 + kk * 32 + lk * 8];
#pragma unroll
      for (int mi = 0; mi < 4; ++mi)
#pragma unroll
        for (int ni = 0; ni < 4; ++ni)
          acc[mi][ni] = __builtin_amdgcn_mfma_f32_16x16x32_bf16(af[mi], bfr[ni], acc[mi][ni], 0, 0, 0);
    }
    __syncthreads();
  }

  float bv[4];
#pragma unroll
  for (int ni = 0; ni < 4; ++ni) bv[ni] = bias[tn + wc * 64 + ni * 16 + lc];

#pragma unroll
  for (int mi = 0; mi < 4; ++mi) {
    const int r0 = tm + wr * 64 + mi * 16 + lk * 4;
#pragma unroll
    for (int j = 0; j < 4; ++j) {
      const int row = r0 + j;
      const long orow = (long)row * Ncols;
#pragma unroll
      for (int ni = 0; ni < 4; ++ni) {
        float v = acc[mi][ni][j] + bv[ni];
        if constexpr (RELU) v = fmaxf(v, 0.f);
        const int c = tn + wc * 64 + ni * 16 + lc;
        outb[orow + c] = __float2bfloat16(v);
      }
    }
  }
}

// ---------------- ff2 GEMM reading ys2 layout, scatter output ----------------
// ys2 element (g,l,k):  byte = ((l*8 + (g>>4))*32 + (k>>4))*512 + (g&15)*32 + (k&15)*2
__global__ __launch_bounds__(256) void k_gemm_ys(
    const uint8_t* __restrict__ Ay, const bf16* __restrict__ Bt,
    const float* __restrict__ bias, const int* __restrict__ gidx,
    float* __restrict__ outf)
{
  __shared__ bf16 lsA[128 * 64];
  __shared__ bf16 lsB[128 * 64];
  const int t = threadIdx.x;
  const int lane = t & 63, wid = t >> 6;
  const int wr = wid >> 1, wc = wid & 1;
  const int tm = blockIdx.y * 128, tn = blockIdx.x * 128;
  const int col8 = (t & 7) * 8;
  const int rsub = t >> 3;
  const int lc = lane & 15, lk = lane >> 4;

  long arow[4], brow[4];
#pragma unroll
  for (int i = 0; i < 4; ++i) {
    const int r = tm + i * 32 + rsub;
    const int g = r >> 9, l = r & 511;
    arow[i] = ((long)l * 8 + (g >> 4)) * 16384 + (g & 15) * 32;
    brow[i] = (long)(tn + i * 32 + rsub) * 512;
  }

  f32x4 acc[4][4];
#pragma unroll
  for (int a = 0; a < 4; ++a)
#pragma unroll
    for (int b = 0; b < 4; ++b) acc[a][b] = (f32x4){0.f, 0.f, 0.f, 0.f};

  for (int ks = 0; ks < 8; ++ks) {
    const int k0 = ks * 64;
    const int kk16 = k0 + col8;
    const long aoff = ((long)(kk16 >> 4) << 9) + ((kk16 & 15) << 1);
#pragma unroll
    for (int i = 0; i < 4; ++i) {
      gld_lds16(Ay + arow[i] + aoff, &lsA[i * 2048 + t * 8]);
      gld_lds16(Bt + brow[i] + k0 + col8, &lsB[i * 2048 + t * 8]);
    }
    __syncthreads();
#pragma unroll
    for (int kk = 0; kk < 2; ++kk) {
      short8 af[4], bfr[4];
#pragma unroll
      for (int mi = 0; mi < 4; ++mi)
        af[mi] = *(const short8*)&lsA[(wr * 64 + mi * 16 + lc) * 64 + kk * 32 + lk * 8];
#pragma unroll
      for (int ni = 0; ni < 4; ++ni)
        bfr[ni] = *(const short8*)&lsB[(wc * 64 + ni * 16 + lc) * 64 + kk * 32 + lk * 8];
#pragma unroll
      for (int mi = 0; mi < 4; ++mi)
#pragma unroll
        for (int ni = 0; ni < 4; ++ni)
          acc[mi][ni] = __builtin_amdgcn_mfma_f32_16x16x32_bf16(af[mi], bfr[ni], acc[mi][ni], 0, 0, 0);
    }
    __syncthreads();
  }

  float bv[4];
#pragma unroll
  for (int ni = 0; ni < 4; ++ni) bv[ni] = bias[tn + wc * 64 + ni * 16 + lc];

#pragma unroll
  for (int mi = 0; mi < 4; ++mi) {
    const int r0 = tm + wr * 64 + mi * 16 + lk * 4;
#pragma unroll
    for (int j = 0; j < 4; ++j) {
      const int row = r0 + j;
      const long orow = (long)gidx[row] * 512;
#pragma unroll
      for (int ni = 0; ni < 4; ++ni) {
        const int c = tn + wc * 64 + ni * 16 + lc;
        outf[orow + c] = acc[mi][ni][j] + bv[ni];
      }
    }
  }
}

// ---------------- persistent GRU (r16/r12 protocol — measured floor) ----------------
// 128 blocks x 128 thr = 8 chains x 32 producers. Operand-swapped MFMA
// (A=W rows=d, B=h cols=groups); ys2 = combined exchange+history (write-once
// per address); gi loads at loop top BEFORE the poll (drain hides under
// producer-wait); padded 128B per-producer flag lines; agent-scope (sc1)
// h store -> vmcnt(0) -> relaxed-agent stamp; consumer polls 32 flags then
// 16 pipelined dwordx4 sc1 loads that ARE the MFMA B-fragments.
// Measured floor: ~8k cyc/step = 512 serial steps x ~3 coherent MALL hops
// x ~2.5k cyc (incl. 32-wave straggler max). Probed and rejected: gi
// reordering (r11: -180us), narrower barrier (r13: -320us), dual-chain
// interleave (r15: -745us), tagged single-hop exchange (r5/r9/r14: slow or
// hang), system-vs-agent scope (r16: null).
__global__ __launch_bounds__(128, 1) void k_gru16(
    const bf16* __restrict__ Whh, const float* __restrict__ bhh,
    const bf16* __restrict__ gi, uint8_t* __restrict__ ys2, int* __restrict__ flags)
{
  __shared__ bf16 lsW[96 * 520];
  const int t = threadIdx.x, lane = t & 63, w = t >> 6;
  const int chain = blockIdx.x >> 4, jcb = blockIdx.x & 15;
  const int lc = lane & 15, lk = lane >> 4;
  const int g0 = chain * 16;
  const int cols0 = jcb * 32;
  const int p = jcb * 2 + w;            // producer / d-tile index 0..31
  const int d0 = p * 16 + lk * 4;       // this lane's 4 consecutive d (group lc)

  // stage W slice (proven layout)
#pragma unroll
  for (int it = 0; it < 48; ++it) {
    const int c = it * 128 + t;
    const int row = c >> 6, col8 = (c & 63) * 8;
    const int e = ((row >> 5) << 9) + cols0 + (row & 31);
    *(uint4*)&lsW[row * 520 + col8] = *(const uint4*)&Whh[(long)e * 512 + col8];
  }
  __syncthreads();

  float bRa[4], bZa[4], bNa[4];
#pragma unroll
  for (int j = 0; j < 4; ++j) {
    bRa[j] = bhh[d0 + j];
    bZa[j] = bhh[512 + d0 + j];
    bNa[j] = bhh[1024 + d0 + j];
  }
  float hreg[4] = {0.f, 0.f, 0.f, 0.f};

  const bf16* gp = gi + (long)(g0 + lc) * 786432 + d0;
  uint8_t* psto = ys2 + (long)chain * 16384 + p * 512 + lc * 32 + lk * 8;
  const long laneoff = (long)(lk >> 1) * 512 + lc * 32 + (lk & 1) * 16;

  int* chflags = flags + chain * 32 * 32;      // 32 producers x 128B stride
  int* myflag  = chflags + p * 32;

  for (int l = 0; l < 512; ++l) {
    u32x2 gRv, gZv, gNv;
    asm volatile("global_load_dwordx2 %0, %1, off"             : "=v"(gRv) : "v"(gp) : "memory");
    asm volatile("global_load_dwordx2 %0, %1, off offset:1024" : "=v"(gZv) : "v"(gp) : "memory");
    asm volatile("global_load_dwordx2 %0, %1, off offset:2048" : "=v"(gNv) : "v"(gp) : "memory");
    gp += 1536;

    f32x4 acc[3] = { (f32x4){0.f,0.f,0.f,0.f}, (f32x4){0.f,0.f,0.f,0.f}, (f32x4){0.f,0.f,0.f,0.f} };
    if (l > 0) {
      int ok;
      do {
        const int v = __hip_atomic_load(&chflags[(lane & 31) * 32], __ATOMIC_RELAXED,
                                        __HIP_MEMORY_SCOPE_AGENT);
        ok = __all(v >= l);
      } while (!ok);
      asm volatile("" ::: "memory");

      const uint8_t* pb = ys2 + ((long)(l - 1) * 8 + chain) * 16384 + laneoff;
      u32x4 hv[16];
#pragma unroll
      for (int q = 0; q < 4; ++q) {
        const uint8_t* pbq = pb + q * 4096;
#pragma unroll
        for (int r2 = 0; r2 < 4; ++r2)
          asm volatile("global_load_dwordx4 %0, %1, off offset:%2 sc1"
                       : "=v"(hv[q * 4 + r2]) : "v"(pbq), "n"(r2 * 1024) : "memory");
      }
      asm volatile("s_waitcnt vmcnt(0)" ::: "memory");
      __builtin_amdgcn_sched_barrier(0);

#pragma unroll
      for (int kk = 0; kk < 16; ++kk) {
        union { u32x4 u; short8 s; } cv;
        cv.u = hv[kk];
#pragma unroll
        for (int gate = 0; gate < 3; ++gate) {
          const short8 wfr = *(const short8*)&lsW[(gate * 32 + w * 16 + lc) * 520 + kk * 32 + lk * 8];
          acc[gate] = __builtin_amdgcn_mfma_f32_16x16x32_bf16(wfr, cv.s, acc[gate], 0, 0, 0);
        }
      }
    } else {
      asm volatile("s_waitcnt vmcnt(0)" ::: "memory");
      __builtin_amdgcn_sched_barrier(0);
    }

    uint32_t hb[4];
#pragma unroll
    for (int j = 0; j < 4; ++j) {
      const uint32_t sh = (j & 1) * 16;
      union { uint32_t u; float f; } cR, cZ, cN;
      cR.u = ((gRv[j >> 1] >> sh) & 0xffffu) << 16;
      cZ.u = ((gZv[j >> 1] >> sh) & 0xffffu) << 16;
      cN.u = ((gNv[j >> 1] >> sh) & 0xffffu) << 16;
      const float r = 1.f / (1.f + __expf(-(cR.f + acc[0][j] + bRa[j])));
      const float z = 1.f / (1.f + __expf(-(cZ.f + acc[1][j] + bZa[j])));
      const float x2 = cN.f + r * (acc[2][j] + bNa[j]);
      const float ex = __expf(2.f * x2);
      const float n = 1.f - 2.f / (ex + 1.f);          // tanh
      const float hn = (1.f - z) * n + z * hreg[j];
      hreg[j] = hn;
      const bf16 hnb = __float2bfloat16(hn);
      hb[j] = (uint32_t)(*(const uint16_t*)&hnb);
    }
    u32x2 hp;
    hp[0] = hb[0] | (hb[1] << 16);
    hp[1] = hb[2] | (hb[3] << 16);
    asm volatile("global_store_dwordx2 %0, %1, off sc1" :: "v"(psto), "v"(hp) : "memory");
    psto += 131072;                                     // next l-slab (8*16384 B)
    asm volatile("s_waitcnt vmcnt(0)" ::: "memory");    // drain the single h store
    if (lane == 0)
      __hip_atomic_store(myflag, l + 1, __ATOMIC_RELAXED, __HIP_MEMORY_SCOPE_AGENT);
  }
}

// ---------------- launch ----------------
extern "C" void kernel_launch(void* const* d_in, const int* in_sizes, int n_in,
                              void* d_out, int out_size, void* d_ws, size_t ws_size,
                              hipStream_t stream)
{
  (void)in_sizes; (void)n_in; (void)out_size; (void)ws_size;
  const float* in_feats = (const float*)d_in[0];
  const int*   e_src    = (const int*)d_in[1];
  const int*   e_dst    = (const int*)d_in[2];
  const int*   seq      = (const int*)d_in[3];
  const float* W_conv   = (const float*)d_in[4];
  const float* b_conv   = (const float*)d_in[5];
  const float* W_ff1    = (const float*)d_in[6];
  const float* b_ff1    = (const float*)d_in[7];
  const float* W_ih     = (const float*)d_in[8];
  const float* W_hh     = (const float*)d_in[9];
  const float* b_ih     = (const float*)d_in[10];
  const float* b_hh     = (const float*)d_in[11];
  const float* W_ff2    = (const float*)d_in[12];
  const float* b_ff2    = (const float*)d_in[13];

  uint8_t* ws = (uint8_t*)d_ws;
  int*  deg     = (int*) (ws + 0);
  int*  cursor  = (int*) (ws + 262144u);
  int*  roff    = (int*) (ws + 524288u);
  bf16* WcT     = (bf16*)(ws + 1048576u);
  bf16* Wf1T    = (bf16*)(ws + 1572864u);
  bf16* Wf2T    = (bf16*)(ws + 2097152u);
  bf16* WihB    = (bf16*)(ws + 2621440u);
  bf16* WhhB    = (bf16*)(ws + 4194304u);
  int*  csr     = (int*) (ws + 6291456u);
  int*  flags   = (int*) (ws + 10485760u);     // 8 chains x 32 producers x 128B = 32KB
  int*  partial = (int*) (ws + 10616832u);     // 64 ints
  int*  sbase   = (int*) (ws + 10620928u);     // 65 ints
  bf16* med2    = (bf16*)(ws + 16777216u);     // 67MB; reused as ys2 after gi GEMM
  uint8_t* ys2  = (uint8_t*)med2;              // [l][chain][p][gl][16dl] bf16 = 64MB
  bf16* gib     = (bf16*)(ws + 83886080u);     // 201MB; aggb/med1/featsb live here pre-gi
  bf16* aggb    = (bf16*)(ws + 83886080u);
  bf16* med1    = (bf16*)(ws + 150994944u);    // also featsb (dead before med1 written)
  bf16* featsb  = (bf16*)(ws + 150994944u);

  hipMemsetAsync(deg,   0, NN * 4,          stream);
  hipMemsetAsync(flags, 0, 8 * 32 * 32 * 4, stream);

  k_prep <<<3072, 256, 0, stream>>>(W_conv, W_ff1, W_ff2, W_ih, W_hh, WcT, Wf1T, Wf2T, WihB, WhhB);
  k_cast <<<NN * DD / 1024, 256, 0, stream>>>(in_feats, featsb);
  k_deg  <<<EE / 256, 256, 0, stream>>>(e_dst, deg);
  k_scan1<<<64, 1024, 0, stream>>>(deg, roff, partial);
  k_scan2<<<1, 64, 0, stream>>>(partial, sbase);
  k_scan3<<<64, 1024, 0, stream>>>(sbase, roff, cursor);
  k_fill <<<EE / 256, 256, 0, stream>>>(e_src, e_dst, cursor, csr);
  k_agg  <<<NN, 128, 0, stream>>>(featsb, csr, roff, aggb);

  dim3 g512(4, 512), g1536(12, 512);
  k_gemm<false, false><<<g512,  256, 0, stream>>>(aggb, WcT,  b_conv, nullptr, med1, 512);
  k_gemm<false, true ><<<g512,  256, 0, stream>>>(med1, Wf1T, b_ff1,  nullptr, med2, 512);
  k_gemm<true,  false><<<g1536, 256, 0, stream>>>(med2, WihB, b_ih,   seq,     gib,  1536);

  k_gru16<<<128, 128, 0, stream>>>(WhhB, b_hh, gib, ys2, flags);

  k_gemm_ys<<<g512, 256, 0, stream>>>(ys2, Wf2T, b_ff2, seq, (float*)d_out);
}